// Round 1
// 248.773 us; speedup vs baseline: 1.6099x; 1.6099x over previous
//
#include <hip/hip_runtime.h>
#include <stdint.h>

#define BN   1024
#define FEATN 512
#define HDIM 256
#define TAUF 5.0f
#define EPSF 1e-8f

typedef __attribute__((ext_vector_type(8))) _Float16 half8;
typedef __attribute__((ext_vector_type(4))) float f32x4;

#if defined(__has_builtin)
#if __has_builtin(__builtin_amdgcn_rcpf)
#define HAVE_RCPF 1
#endif
#endif

#ifdef HAVE_RCPF
__device__ __forceinline__ float fast_rcp(float x) { return __builtin_amdgcn_rcpf(x); }
#else
__device__ __forceinline__ float fast_rcp(float x) { return 1.0f / x; }
#endif

// tanh-approx gelu == x * sigmoid(1.5957691x + 0.0713548x^3)
__device__ __forceinline__ float gelu_fast(float x) {
  float s = fmaf(x * x, 0.07135481627f, 1.59576912161f) * x;
  float e = __expf(s);
  return x * e * fast_rcp(e + 1.0f);
}

// ---------------- prep: W1[:512] -> fp16 frag order; label softmax ----------------
__global__ __launch_bounds__(256) void prep_kernel(const float* __restrict__ W1,
                                                   const float* __restrict__ lg,
                                                   _Float16* __restrict__ w1h,
                                                   float* __restrict__ oh) {
  int b = blockIdx.x, t = threadIdx.x;
  if (b < FEATN) {
    int k = b, n = t;
    // B-frag layout: element (k,n) at ((k>>3)*256 + n)*8 + (k&7)
    w1h[(((k >> 3) * HDIM) + n) * 8 + (k & 7)] = (_Float16)W1[k * HDIM + n];
  } else {
    int i = (b - FEATN) * 256 + t;
    float l0 = lg[2 * i], l1 = lg[2 * i + 1];
    float m = fmaxf(l0, l1);
    float e0 = __expf(l0 - m), e1 = __expf(l1 - m);
    float inv = 1.0f / (e0 + e1);
    oh[2 * i] = e0 * inv;
    oh[2 * i + 1] = e1 * inv;
  }
}

// ---------------- main: fused pair-GEMM (fp16 MFMA) + gelu + W2-dot + sigmoid ----------------
// h_scores is SYMMETRIC (|Xi-Xj| and label product are symmetric, bitwise), so only
// lower-triangle 8x8-pair tiles are computed (grid 65x128 rectangle folded onto the
// 128x129/2 triangle); each block writes its tile AND the shfl-transposed mirror tile.
// Tile: 64 pairs (8i x 8j) x 256 n. Waves split n (unique B per wave). A-frags shared via
// double-buffered sA in 2-step chunks -> ONE barrier per 2 k-steps. X staged as fp16.
__global__ __launch_bounds__(256, 4) void gemm_kernel(const float* __restrict__ X,
                                                      const _Float16* __restrict__ w1h,
                                                      const float* __restrict__ oh,
                                                      const float* __restrict__ W1,
                                                      const float* __restrict__ b1,
                                                      const float* __restrict__ W2,
                                                      const float* __restrict__ b2,
                                                      float* __restrict__ out_hs) {
  __shared__ __align__(16) _Float16 sX[16 * 520];     // rows 0-7: i, 8-15: j (stride 520 fp16)
  __shared__ __align__(16) half8 sA[2][2][4][64];     // [buf][step-in-chunk][m-subtile][lane]
  __shared__ float sScore[64 * 4];
  __shared__ float sLab0[64], sLab1[64];

  const int tid = threadIdx.x;
  const int L = tid & 63;
  const int w = tid >> 6;              // wave id == n-quarter AND construct m-subtile

  // triangle fold: map grid (x in [0,65), y in [0,128)) onto lower-tri tiles (bi >= bj).
  // Seam column (bj==64, bi>=64) is covered twice -> idempotent (bitwise-equal values).
  int bi = blockIdx.y, bj = blockIdx.x;
  if (bj > bi) { bi = 127 - bi; bj = 128 - bj; }
  const int i0 = bi * 8;
  const int j0 = bj * 8;

  // ---- stage 16 X rows, f32 -> fp16 (RTNE), LDS stride 520 fp16 ----
  #pragma unroll
  for (int it = 0; it < 4; ++it) {
    int idx = tid + it * 256;          // 1024 octet tasks (16 rows x 64 octets)
    int row = idx >> 6;
    int oc = idx & 63;
    int grow = (row < 8) ? (i0 + row) : (j0 + row - 8);
    const float* gp = X + grow * FEATN + oc * 8;
    float4 a = *(const float4*)gp;
    float4 c = *(const float4*)(gp + 4);
    half8 hv;
    hv[0] = (_Float16)a.x; hv[1] = (_Float16)a.y; hv[2] = (_Float16)a.z; hv[3] = (_Float16)a.w;
    hv[4] = (_Float16)c.x; hv[5] = (_Float16)c.y; hv[6] = (_Float16)c.z; hv[7] = (_Float16)c.w;
    *(half8*)(sX + row * 520 + oc * 8) = hv;
  }
  if (tid < 64) {
    int gi = i0 + (tid >> 3), gj = j0 + (tid & 7);
    sLab0[tid] = oh[2 * gi] * oh[2 * gj];
    sLab1[tid] = oh[2 * gi + 1] * oh[2 * gj + 1];
  }

  // ---- construct decode: wave w builds m-subtile w's frag for lane L ----
  // pair m = 16w + (L&15); ii = 2w + ((L&15)>>3); jj = L&7; koct = L>>4
  const int nl = L & 15;
  const int koct = L >> 4;
  const _Float16* cxi = sX + (2 * w + (nl >> 3)) * 520 + koct * 8;
  const _Float16* cxj = sX + (8 + (L & 7)) * 520 + koct * 8;

  // B-frag per-lane base (fp16 elems): step kt at +kt*8192, n-subtile u at +u*128
  const _Float16* bbase = w1h + ((koct * HDIM) + w * 64 + nl) * 8;

  f32x4 acc[4][4];
  #pragma unroll
  for (int s = 0; s < 4; ++s)
    #pragma unroll
    for (int u = 0; u < 4; ++u) acc[s][u] = (f32x4){0.f, 0.f, 0.f, 0.f};

  __syncthreads();

  // construct one step's A-frag (fp16 pk-sub + abs mask) into sA[buf][st]
  #define CONSTRUCT(kt, buf, st)                                          \
    {                                                                     \
      half8 xi = *(const half8*)(cxi + (kt) * 32);                        \
      half8 xj = *(const half8*)(cxj + (kt) * 32);                        \
      union { half8 h; unsigned u4[4]; } U;                               \
      U.h = xi - xj;                                                      \
      U.u4[0] &= 0x7FFF7FFFu; U.u4[1] &= 0x7FFF7FFFu;                     \
      U.u4[2] &= 0x7FFF7FFFu; U.u4[3] &= 0x7FFF7FFFu;                     \
      sA[buf][st][w][L] = U.h;                                            \
    }

  #define CONSUME(kt, buf, st)                                            \
    {                                                                     \
      half8 afr[4];                                                       \
      _Pragma("unroll")                                                   \
      for (int s = 0; s < 4; ++s) afr[s] = sA[buf][st][s][L];             \
      half8 bfr[4];                                                       \
      _Pragma("unroll")                                                   \
      for (int u = 0; u < 4; ++u)                                         \
        bfr[u] = *(const half8*)(bbase + (kt) * 8192 + u * 128);          \
      _Pragma("unroll")                                                   \
      for (int s = 0; s < 4; ++s)                                         \
        _Pragma("unroll")                                                 \
        for (int u = 0; u < 4; ++u)                                       \
          acc[s][u] = __builtin_amdgcn_mfma_f32_16x16x32_f16(             \
              afr[s], bfr[u], acc[s][u], 0, 0, 0);                        \
    }

  // prologue: chunk 0 (steps 0,1)
  CONSTRUCT(0, 0, 0)
  CONSTRUCT(1, 0, 1)
  __syncthreads();

  #pragma unroll 2
  for (int t = 0; t < 8; ++t) {
    const int buf = t & 1;
    CONSUME(2 * t, buf, 0)
    CONSUME(2 * t + 1, buf, 1)
    if (t < 7) {
      CONSTRUCT(2 * t + 2, 1 - buf, 0)
      CONSTRUCT(2 * t + 3, 1 - buf, 1)
    }
    __syncthreads();
  }
  #undef CONSTRUCT
  #undef CONSUME

  // ---- epilogue: + label rank-2 + b1, fast gelu, dot W2, reduce, sigmoid ----
  const int q = L >> 4;
  float w1l0[4], w1l1[4], bb1[4], ww2[4];
  #pragma unroll
  for (int u = 0; u < 4; ++u) {
    int n = w * 64 + u * 16 + nl;
    w1l0[u] = W1[512 * HDIM + n];
    w1l1[u] = W1[513 * HDIM + n];
    bb1[u] = b1[n];
    ww2[u] = W2[n];
  }
  #pragma unroll
  for (int s = 0; s < 4; ++s) {
    #pragma unroll
    for (int r = 0; r < 4; ++r) {
      int m = s * 16 + q * 4 + r;     // C/D: row = quad*4 + reg
      float l0v = sLab0[m], l1v = sLab1[m];
      float v = 0.f;
      #pragma unroll
      for (int u = 0; u < 4; ++u) {
        float e = acc[s][u][r] + l0v * w1l0[u] + l1v * w1l1[u] + bb1[u];
        v += gelu_fast(e) * ww2[u];
      }
      v += __shfl_xor(v, 1, 64);
      v += __shfl_xor(v, 2, 64);
      v += __shfl_xor(v, 4, 64);
      v += __shfl_xor(v, 8, 64);       // sum over 16 lanes of the quad
      if (nl == 0) sScore[m * 4 + w] = v;
    }
  }
  __syncthreads();
  if (tid < 64) {
    float s4 = sScore[tid * 4 + 0] + sScore[tid * 4 + 1] + sScore[tid * 4 + 2] +
               sScore[tid * 4 + 3] + b2[0];
    float hsv = fast_rcp(1.0f + __expf(-s4));
    int r = tid >> 3, c = tid & 7;
    out_hs[(size_t)(i0 + r) * BN + (j0 + c)] = hsv;
    if (i0 != j0) {
      // mirror tile: element (j0+r, i0+c) = hsv of pair (i0+c, j0+r) = lane (c*8+r)
      float tv = __shfl(hsv, (c << 3) | r, 64);
      out_hs[(size_t)(j0 + r) * BN + (i0 + c)] = tv;
    }
  }
}

// ---------------- row softmax of adj + TAU*log(hs + EPS) ----------------
__global__ __launch_bounds__(256) void softmax_kernel(const float* __restrict__ adj,
                                                      const float* __restrict__ hs,
                                                      float* __restrict__ out) {
  int i = blockIdx.x, t = threadIdx.x;
  __shared__ float redm[4];
  __shared__ float reds[4];
  float l[4];
  float mx = -1e30f;
  #pragma unroll
  for (int k = 0; k < 4; ++k) {
    int j = t + k * 256;
    float lv = adj[(size_t)i * BN + j] + TAUF * __logf(hs[(size_t)i * BN + j] + EPSF);
    l[k] = lv;
    mx = fmaxf(mx, lv);
  }
  #pragma unroll
  for (int o = 1; o <= 32; o <<= 1) mx = fmaxf(mx, __shfl_xor(mx, o, 64));
  if ((t & 63) == 0) redm[t >> 6] = mx;
  __syncthreads();
  mx = fmaxf(fmaxf(redm[0], redm[1]), fmaxf(redm[2], redm[3]));
  float ex[4];
  float se = 0.f;
  #pragma unroll
  for (int k = 0; k < 4; ++k) { ex[k] = __expf(l[k] - mx); se += ex[k]; }
  #pragma unroll
  for (int o = 1; o <= 32; o <<= 1) se += __shfl_xor(se, o, 64);
  if ((t & 63) == 0) reds[t >> 6] = se;
  __syncthreads();
  se = reds[0] + reds[1] + reds[2] + reds[3];
  float inv = fast_rcp(se);
  #pragma unroll
  for (int k = 0; k < 4; ++k) out[(size_t)i * BN + t + k * 256] = ex[k] * inv;
}

extern "C" void kernel_launch(void* const* d_in, const int* in_sizes, int n_in,
                              void* d_out, int out_size, void* d_ws, size_t ws_size,
                              hipStream_t stream) {
  (void)in_sizes; (void)n_in; (void)out_size; (void)ws_size;
  const float* X   = (const float*)d_in[0];
  const float* lg  = (const float*)d_in[1];
  const float* adj = (const float*)d_in[2];
  const float* W1  = (const float*)d_in[3];
  const float* b1  = (const float*)d_in[4];
  const float* W2  = (const float*)d_in[5];
  const float* b2  = (const float*)d_in[6];
  float* out = (float*)d_out;                       // [0,B^2): adj_refined, [B^2,2B^2): h_scores
  _Float16* w1h = (_Float16*)d_ws;                  // 512*256 fp16 = 256 KB
  float* oh = (float*)((char*)d_ws + FEATN * HDIM * 2);  // 1024*2 f32

  float* out_hs = out + (size_t)BN * BN;

  prep_kernel<<<dim3(FEATN + 4), dim3(256), 0, stream>>>(W1, lg, w1h, oh);
  // lower-triangle tiles only (h_scores is symmetric): 65x128 rectangle folds onto triangle
  gemm_kernel<<<dim3(65, 128), dim3(256), 0, stream>>>(X, w1h, oh, W1, b1, W2, b2, out_hs);
  softmax_kernel<<<dim3(BN), dim3(256), 0, stream>>>(adj, out_hs, out);
}